// Round 20
// baseline (69.341 us; speedup 1.0000x reference)
//
#include <hip/hip_runtime.h>
#include <hip/hip_fp16.h>

// RotMat forward: 511 rounds of 256 disjoint Givens rotations on rows of a
// [512, 1024] fp32 matrix (round-robin tournament schedule).
//
// R19: SEGMENT DECOMPOSITION, 255+255+1. out = G510 * (Q1 * (Q0 * x)),
// Q0 = rounds 0..254, Q1 = rounds 255..509, G510 = round 510 applied by a
// trivial in-place rotation kernel. BOTH builds are byte-for-byte the PROVEN
// monolithic chunk sequence (15 x CHUNK16 + CHUNK15_TAIL, fully WL-drained,
// uniform control flow) -- R17/R18's seg0 256-round path needed a novel
// CHUNK16 ending (dead ANXT reads + DRAINL) which is the prime suspect for
// R18's absmax=2.83; that structure no longer exists.
// Maps: position p at round r holds row player_of(r,p) = (p==0)?0:
// ((p-1-r) mod 511)+1. Init: state[p] = e_j[player_of(r0,p)]; write:
// Q[player_of(r1,p)][j] = state[p] (verified: theta=0 gives Q=I exactly).
// ws: [0,512K) f16 table | [512K,1.5M) Q0T | [1.5M,2.5M) Q1T | [2.5M,4.5M) Y.
// Fallback to proven monolithic (46.4us) if ws too small.

#define N_COLS   1024
#define PAIRS    256

typedef __attribute__((ext_vector_type(4))) float f32x4;

// ---- setup: f16-packed (c,s) table, round r at byte r*1024, pair k at +k*4.
__global__ __launch_bounds__(256) void rotmat_setup(const float* __restrict__ thetas,
                                                    __half2* __restrict__ cs16) {
    const int r = blockIdx.x;   // 0..510
    const int k = threadIdx.x;  // 0..255
    int pu = (k == 0) ? 0 : ((k - 1 - r + 1022) % 511) + 1;
    int pv = ((510 - k - r + 1022) % 511) + 1;
    int i = min(pu, pv), j = max(pu, pv);
    int t = i * 511 - (i * (i - 1)) / 2 + (j - i - 1);
    float s, c;
    sincosf(thetas[t], &s, &c);
    float sp = (pu < pv) ? s : -s;
    cs16[r * 256 + k] = __floats2half2_rn(c, sp);
}

__device__ __forceinline__ float dpp_shr1(float old, float src) {
    return __int_as_float(__builtin_amdgcn_update_dpp(
        __float_as_int(old), __float_as_int(src), 0x138, 0xF, 0xF, false));
}
__device__ __forceinline__ float dpp_shl1(float old, float src) {
    return __int_as_float(__builtin_amdgcn_update_dpp(
        __float_as_int(old), __float_as_int(src), 0x130, 0xF, 0xF, false));
}
__device__ __forceinline__ void glds16(const void* g, void* l) {
    __builtin_amdgcn_global_load_lds(
        (const __attribute__((address_space(1))) void*)g,
        (__attribute__((address_space(3))) void*)l, 16, 0, 0);
}

// v_fma_mix_f32 coefficient consumption (R16-validated).
#define FMIX_SN(d, P, x)                                                      \
    asm("v_fma_mix_f32 %0, -%1, %2, 0 op_sel:[1,0,0] op_sel_hi:[1,0,0]"       \
        : "=v"(d) : "v"(P), "v"(x));
#define FMIX_SP(d, P, x)                                                      \
    asm("v_fma_mix_f32 %0, %1, %2, 0 op_sel:[1,0,0] op_sel_hi:[1,0,0]"        \
        : "=v"(d) : "v"(P), "v"(x));
#define FMIX_C(d, P, x, a)                                                    \
    asm("v_fma_mix_f32 %0, %1, %2, %3 op_sel:[0,0,0] op_sel_hi:[1,0,0]"       \
        : "=v"(d) : "v"(P), "v"(x), "v"(a));

#define ROUND(AA)                                                  \
    {                                                              \
        float P0 = (AA).x, P1 = (AA).y, P2 = (AA).z, P3 = (AA).w;  \
        float t3, u3, l3, h3, t0, u0, l0, h0;                      \
        FMIX_SN(t3, P3, hi[3])                                     \
        FMIX_C(l3, P3, lo[3], t3)                                  \
        FMIX_SP(u3, P3, lo[3])                                     \
        FMIX_C(h3, P3, hi[3], u3)                                  \
        FMIX_SN(t0, P0, hi[0])                                     \
        FMIX_C(l0, P0, lo[0], t0)                                  \
        FMIX_SP(u0, P0, lo[0])                                     \
        FMIX_C(h0, P0, hi[0], u0)                                  \
        float nlo0 = dpp_shr1(l0, l3);                             \
        float nhi3 = dpp_shl1(l3, h0);                             \
        float t1, u1, l1, h1, t2, u2, l2, h2;                      \
        FMIX_SN(t1, P1, hi[1])                                     \
        FMIX_C(l1, P1, lo[1], t1)                                  \
        FMIX_SP(u1, P1, lo[1])                                     \
        FMIX_C(h1, P1, hi[1], u1)                                  \
        FMIX_SN(t2, P2, hi[2])                                     \
        FMIX_C(l2, P2, lo[2], t2)                                  \
        FMIX_SP(u2, P2, lo[2])                                     \
        FMIX_C(h2, P2, hi[2], u2)                                  \
        float nlo1 = is0 ? h0 : l0;                                \
        lo[0] = nlo0; lo[1] = nlo1; lo[2] = l1; lo[3] = l2;        \
        hi[0] = h1; hi[1] = h2; hi[2] = h3; hi[3] = nhi3;          \
    }

#define DSRD(dst, addr, imm)                                   \
    asm volatile("ds_read_b128 %0, %1 offset:%c2"              \
                 : "=v"(dst) : "v"(addr), "i"(imm))
#define WL3(a) asm volatile("s_waitcnt lgkmcnt(3)" : "+v"(a))
#define WL2(a) asm volatile("s_waitcnt lgkmcnt(2)" : "+v"(a))
#define WL1(a) asm volatile("s_waitcnt lgkmcnt(1)" : "+v"(a))
#define WL0(a) asm volatile("s_waitcnt lgkmcnt(0)" : "+v"(a))
#define WAITV(n) asm volatile("s_waitcnt vmcnt(" #n ")" ::: "memory")
#define BAR()                               \
    __builtin_amdgcn_s_barrier();           \
    __builtin_amdgcn_sched_barrier(0)

#define STAGE(cix, bix)                                              \
    {                                                                \
        const char* g_ = gsrc + (size_t)(cix)*16384;                 \
        char* l_ = lb + (size_t)(bix)*16384;                         \
        _Pragma("unroll")                                            \
        for (int j_ = 0; j_ < 4; ++j_)                               \
            glds16(g_ + j_ * 1024, l_ + j_ * 1024);                  \
    }

#define CHUNK16(ACUR, ANXT)                                    \
    WL3(A0); ROUND(A0) DSRD(A0, ACUR,  4 * 1024);              \
    WL3(A1); ROUND(A1) DSRD(A1, ACUR,  5 * 1024);              \
    WL3(A2); ROUND(A2) DSRD(A2, ACUR,  6 * 1024);              \
    WL3(A3); ROUND(A3) DSRD(A3, ACUR,  7 * 1024);              \
    WL3(A0); ROUND(A0) DSRD(A0, ACUR,  8 * 1024);              \
    WL3(A1); ROUND(A1) DSRD(A1, ACUR,  9 * 1024);              \
    WL3(A2); ROUND(A2) DSRD(A2, ACUR, 10 * 1024);              \
    WL3(A3); ROUND(A3) DSRD(A3, ACUR, 11 * 1024);              \
    WL3(A0); ROUND(A0) DSRD(A0, ACUR, 12 * 1024);              \
    WL3(A1); ROUND(A1) DSRD(A1, ACUR, 13 * 1024);              \
    WL3(A2); ROUND(A2) DSRD(A2, ACUR, 14 * 1024);              \
    WL3(A3); ROUND(A3) DSRD(A3, ACUR, 15 * 1024);              \
    WL3(A0); ROUND(A0) DSRD(A0, ANXT,  0 * 1024);              \
    WL3(A1); ROUND(A1) DSRD(A1, ANXT,  1 * 1024);              \
    WL3(A2); ROUND(A2) DSRD(A2, ANXT,  2 * 1024);              \
    WL3(A3); ROUND(A3) DSRD(A3, ANXT,  3 * 1024);

// 15-round tail (rounds base..base+14; round base+15 staged, never read).
// Ends fully drained (WL0) -- endpgm-safe.
#define CHUNK15_TAIL(ACUR)                                     \
    WL3(A0); ROUND(A0) DSRD(A0, ACUR,  4 * 1024);              \
    WL3(A1); ROUND(A1) DSRD(A1, ACUR,  5 * 1024);              \
    WL3(A2); ROUND(A2) DSRD(A2, ACUR,  6 * 1024);              \
    WL3(A3); ROUND(A3) DSRD(A3, ACUR,  7 * 1024);              \
    WL3(A0); ROUND(A0) DSRD(A0, ACUR,  8 * 1024);              \
    WL3(A1); ROUND(A1) DSRD(A1, ACUR,  9 * 1024);              \
    WL3(A2); ROUND(A2) DSRD(A2, ACUR, 10 * 1024);              \
    WL3(A3); ROUND(A3) DSRD(A3, ACUR, 11 * 1024);              \
    WL3(A0); ROUND(A0) DSRD(A0, ACUR, 12 * 1024);              \
    WL3(A1); ROUND(A1) DSRD(A1, ACUR, 13 * 1024);              \
    WL3(A2); ROUND(A2) DSRD(A2, ACUR, 14 * 1024);              \
    WL3(A3); ROUND(A3)                                         \
    WL2(A0); ROUND(A0)                                         \
    WL1(A1); ROUND(A1)                                         \
    WL0(A2); ROUND(A2)

// player(r, p): row carried at position p at the start of round r.
__device__ __forceinline__ int player_of(int r, int p) {
    return (p == 0) ? 0 : ((p - 1 - r + 1022) % 511) + 1;
}

// ---- build: both 255-round segment operators, 1024 waves ------------------
// seg = wid>>9 (block-uniform), j = wid&511. seg0: rounds 0..254 (r0=0,
// r1=255); seg1: rounds 255..509 (r0=255, r1=510). QT[seg][j][row], K-major.
// Chunk schedule: EXACTLY the proven monolithic shape (uniform, tail-ended).
__global__ __launch_bounds__(256, 1) void rotmat_build(const __half2* __restrict__ cs16,
                                                       float* __restrict__ qt) {
    __shared__ f32x4 tab[3 * 1024];  // 48KB

    const int lane = threadIdx.x & 63;
    const int wave = threadIdx.x >> 6;
    const int wid  = (blockIdx.x << 2) + wave;
    const int seg  = wid >> 9;            // 0 or 1 (uniform per block)
    const int j    = wid & 511;
    const int r0   = seg ? 255 : 0;
    const int k0   = lane << 2;
    const bool is0 = (lane == 0);

    float lo[4], hi[4];
#pragma unroll
    for (int m = 0; m < 4; ++m) {
        int p = k0 + m, pq = 511 - p;
        lo[m] = (player_of(r0, p) == j) ? 1.0f : 0.0f;
        hi[m] = (player_of(r0, pq) == j) ? 1.0f : 0.0f;
    }

    const char* gsrc = (const char*)cs16 + (size_t)r0 * 1024
                     + (size_t)wave * 4096 + (size_t)lane * 16;
    char* lb = (char*)(&tab[0]) + (size_t)wave * 4096;
    unsigned ldsLane;
    {
        auto p3 = (__attribute__((address_space(3))) char*)(&tab[0]);
        ldsLane = (unsigned)(size_t)p3 + (unsigned)(lane * 16);
    }

    f32x4 A0, A1, A2, A3;

    // Prologue: stage chunks 0,1; landed; sync; pre-issue rounds 0..3.
    STAGE(0, 0)
    STAGE(1, 1)
    WAITV(0);
    BAR();
    {
        unsigned a0 = ldsLane;
        DSRD(A0, a0, 0 * 1024);
        DSRD(A1, a0, 1 * 1024);
        DSRD(A2, a0, 2 * 1024);
        DSRD(A3, a0, 3 * 1024);
    }

    // Chunks 0..13 (loop, staging 2..15), chunk 14, chunk-15 tail = 255 rounds.
    int bufCur = 0, bufNxt = 1, bufStg = 2;
    for (int c = 0; c < 14; ++c) {
        WAITV(0);
        BAR();
        STAGE(c + 2, bufStg)
        unsigned aCur = ldsLane + (unsigned)bufCur * 16384u;
        unsigned aNxt = ldsLane + (unsigned)bufNxt * 16384u;
        CHUNK16(aCur, aNxt)
        int t_ = bufCur; bufCur = bufNxt; bufNxt = bufStg; bufStg = t_;
    }
    {
        WAITV(0);   // stage(15) landed (issued at c=13)
        BAR();
        unsigned aCur = ldsLane + (unsigned)bufCur * 16384u;
        unsigned aNxt = ldsLane + (unsigned)bufNxt * 16384u;
        CHUNK16(aCur, aNxt)
        int t_ = bufCur; bufCur = bufNxt; bufNxt = bufStg; bufStg = t_;
    }
    {
        unsigned aCur = ldsLane + (unsigned)bufCur * 16384u;
        CHUNK15_TAIL(aCur)   // relative rounds 240..254; ends drained
    }

    // Write Q_seg^T: row = player(r1, p).
    const int r1 = seg ? 510 : 255;
    float* qv = qt + (size_t)seg * 262144 + (size_t)j * 512;
#pragma unroll
    for (int m = 0; m < 4; ++m) {
        int p = k0 + m, pq = 511 - p;
        qv[player_of(r1, p)]  = lo[m];
        qv[player_of(r1, pq)] = hi[m];
    }
}

// ---- apply: C[512][1024] = sum_j AT[j][row] * B[j][col] -------------------
// AT K-major [512][512]; B row-major [512][1024]. BM=32, BN=64, BK=32.
__global__ __launch_bounds__(256) void gemm_qt(const float* __restrict__ AT,
                                               const float* __restrict__ B,
                                               float* __restrict__ C) {
    __shared__ float As[32][32];   // [k][m]
    __shared__ float Bs[32][64];   // [k][n]

    const int t    = threadIdx.x;
    const int bx   = blockIdx.x & 15;   // col tile (64 wide)
    const int by   = blockIdx.x >> 4;   // row tile (32 tall)
    const int row0 = by * 32, col0 = bx * 64;
    const int mr   = (t & 15) * 2;
    const int nc   = (t >> 4) * 4;

    float acc00 = 0, acc01 = 0, acc02 = 0, acc03 = 0;
    float acc10 = 0, acc11 = 0, acc12 = 0, acc13 = 0;

    for (int kt = 0; kt < 16; ++kt) {
        __syncthreads();
        {
            int kk = t >> 3, mm = (t & 7) * 4;
            *(float4*)&As[kk][mm] =
                *(const float4*)&AT[(size_t)(kt * 32 + kk) * 512 + row0 + mm];
        }
        {
            int kk = t >> 4, cc = (t & 15) * 4;
            *(float4*)&Bs[kk][cc] =
                *(const float4*)&B[(size_t)(kt * 32 + kk) * 1024 + col0 + cc];
            *(float4*)&Bs[kk + 16][cc] =
                *(const float4*)&B[(size_t)(kt * 32 + kk + 16) * 1024 + col0 + cc];
        }
        __syncthreads();
#pragma unroll
        for (int kk = 0; kk < 32; ++kk) {
            float a0 = As[kk][mr], a1 = As[kk][mr + 1];
            float4 b = *(float4*)&Bs[kk][nc];
            acc00 = fmaf(a0, b.x, acc00); acc01 = fmaf(a0, b.y, acc01);
            acc02 = fmaf(a0, b.z, acc02); acc03 = fmaf(a0, b.w, acc03);
            acc10 = fmaf(a1, b.x, acc10); acc11 = fmaf(a1, b.y, acc11);
            acc12 = fmaf(a1, b.z, acc12); acc13 = fmaf(a1, b.w, acc13);
        }
    }
    *(float4*)&C[(size_t)(row0 + mr) * 1024 + col0 + nc] =
        make_float4(acc00, acc01, acc02, acc03);
    *(float4*)&C[(size_t)(row0 + mr + 1) * 1024 + col0 + nc] =
        make_float4(acc10, acc11, acc12, acc13);
}

// ---- final round 510, in place on out (disjoint row pairs, fp32 thetas) ---
__global__ __launch_bounds__(256) void round_last(const float* __restrict__ thetas,
                                                  float* __restrict__ out) {
    const int k = blockIdx.x;  // pair 0..255 (positions k, 511-k at round 510)
    int pu = (k == 0) ? 0 : ((k - 1 - 510 + 1022) % 511) + 1;
    int pv = ((510 - k - 510 + 1022) % 511) + 1;
    int i = min(pu, pv), jj = max(pu, pv);
    int t = i * 511 - (i * (i - 1)) / 2 + (jj - i - 1);
    float s, c;
    sincosf(thetas[t], &s, &c);
    float* ri = out + (size_t)i * 1024;
    float* rj = out + (size_t)jj * 1024;
#pragma unroll
    for (int u = 0; u < 4; ++u) {
        int col = threadIdx.x + u * 256;
        float a = ri[col], b = rj[col];
        ri[col] = fmaf(c, a, -(s * b));   // row i: c*x[i] - s*x[j]
        rj[col] = fmaf(s, a, c * b);      // row j: s*x[i] + c*x[j]
    }
}

// ---- fallback monolithic kernel (R16-proven, 46.4us) ----------------------
template <bool TAB>
__global__ __launch_bounds__(256, 1) void rotmat_main(const float* __restrict__ x,
                                                      const float* __restrict__ thetas,
                                                      const __half2* __restrict__ cs16,
                                                      float* __restrict__ out) {
    __shared__ f32x4 tab[3 * 1024];

    const int lane = threadIdx.x & 63;
    const int wave = threadIdx.x >> 6;
    const int col  = (blockIdx.x << 2) + wave;
    const int k0   = lane << 2;
    const bool is0 = (lane == 0);

    float lo[4], hi[4];
#pragma unroll
    for (int m = 0; m < 4; ++m) {
        lo[m] = x[(k0 + m) * N_COLS + col];
        hi[m] = x[(511 - k0 - m) * N_COLS + col];
    }

    if constexpr (TAB) {
        const char* gsrc = (const char*)cs16 + (size_t)wave * 4096 + (size_t)lane * 16;
        char* lb = (char*)(&tab[0]) + (size_t)wave * 4096;
        unsigned ldsLane;
        {
            auto p3 = (__attribute__((address_space(3))) char*)(&tab[0]);
            ldsLane = (unsigned)(size_t)p3 + (unsigned)(lane * 16);
        }
        f32x4 A0, A1, A2, A3;
        STAGE(0, 0)
        STAGE(1, 1)
        WAITV(0);
        BAR();
        {
            unsigned a0 = ldsLane;
            DSRD(A0, a0, 0 * 1024);
            DSRD(A1, a0, 1 * 1024);
            DSRD(A2, a0, 2 * 1024);
            DSRD(A3, a0, 3 * 1024);
        }
        int bufCur = 0, bufNxt = 1, bufStg = 2;
        for (int c = 0; c < 30; ++c) {
            WAITV(0);
            BAR();
            STAGE(c + 2, bufStg)
            unsigned aCur = ldsLane + (unsigned)bufCur * 16384u;
            unsigned aNxt = ldsLane + (unsigned)bufNxt * 16384u;
            CHUNK16(aCur, aNxt)
            int t_ = bufCur; bufCur = bufNxt; bufNxt = bufStg; bufStg = t_;
        }
        {
            WAITV(0);
            BAR();
            unsigned aCur = ldsLane + (unsigned)bufCur * 16384u;
            unsigned aNxt = ldsLane + (unsigned)bufNxt * 16384u;
            CHUNK16(aCur, aNxt)
            int t_ = bufCur; bufCur = bufNxt; bufNxt = bufStg; bufStg = t_;
        }
        {
            unsigned aCur = ldsLane + (unsigned)bufCur * 16384u;
            CHUNK15_TAIL(aCur)
        }
    } else {
        int pu[4], pv[4];
#pragma unroll
        for (int m = 0; m < 4; ++m) {
            pu[m] = (k0 + m == 0) ? 0 : (k0 + m);
            pv[m] = 511 - (k0 + m);
        }
        for (int r = 0; r < 511; ++r) {
            float cc[4], ss[4];
#pragma unroll
            for (int m = 0; m < 4; ++m) {
                int i = min(pu[m], pv[m]), jj = max(pu[m], pv[m]);
                int t = i * 511 - (i * (i - 1)) / 2 + (jj - i - 1);
                float s, c;
                sincosf(thetas[t], &s, &c);
                cc[m] = c;
                ss[m] = (pu[m] < pv[m]) ? s : -s;
            }
            {
                float t3 = ss[3] * hi[3], u3 = ss[3] * lo[3];
                float l3 = fmaf(cc[3], lo[3], -t3);
                float h3 = fmaf(cc[3], hi[3], u3);
                float t0 = ss[0] * hi[0], u0 = ss[0] * lo[0];
                float l0 = fmaf(cc[0], lo[0], -t0);
                float h0 = fmaf(cc[0], hi[0], u0);
                float nlo0 = dpp_shr1(l0, l3);
                float nhi3 = dpp_shl1(l3, h0);
                float t1 = ss[1] * hi[1], u1 = ss[1] * lo[1];
                float l1 = fmaf(cc[1], lo[1], -t1);
                float h1 = fmaf(cc[1], hi[1], u1);
                float t2 = ss[2] * hi[2], u2 = ss[2] * lo[2];
                float l2 = fmaf(cc[2], lo[2], -t2);
                float h2 = fmaf(cc[2], hi[2], u2);
                float nlo1 = is0 ? h0 : l0;
                lo[0] = nlo0; lo[1] = nlo1; lo[2] = l1; lo[3] = l2;
                hi[0] = h1; hi[1] = h2; hi[2] = h3; hi[3] = nhi3;
            }
#pragma unroll
            for (int m = 0; m < 4; ++m) {
                pu[m] = (k0 + m == 0) ? 0 : ((pu[m] == 1) ? 511 : pu[m] - 1);
                pv[m] = (pv[m] == 1) ? 511 : pv[m] - 1;
            }
        }
    }

#pragma unroll
    for (int m = 0; m < 4; ++m) {
        out[(k0 + m) * N_COLS + col]       = lo[m];
        out[(511 - k0 - m) * N_COLS + col] = hi[m];
    }
}

extern "C" void kernel_launch(void* const* d_in, const int* in_sizes, int n_in,
                              void* d_out, int out_size, void* d_ws, size_t ws_size,
                              hipStream_t stream) {
    const float* x  = (const float*)d_in[0];
    const float* th = (const float*)d_in[1];
    float* out      = (float*)d_out;

    const size_t TAB_B = (size_t)512 * 1024;          // 512 KiB f16 table
    const size_t Q_B   = (size_t)512 * 512 * 4;       // 1 MiB per segment
    const size_t Y_B   = (size_t)512 * 1024 * 4;      // 2 MiB intermediate
    const size_t need_decomp = TAB_B + 2 * Q_B + Y_B; // 4,718,592

    if (ws_size >= need_decomp) {
        __half2* cs16 = (__half2*)d_ws;
        float* qt = (float*)((char*)d_ws + TAB_B);          // Q0T then Q1T
        float* Y  = (float*)((char*)d_ws + TAB_B + 2 * Q_B);
        rotmat_setup<<<511, PAIRS, 0, stream>>>(th, cs16);
        rotmat_build<<<256, 256, 0, stream>>>(cs16, qt);
        gemm_qt<<<256, 256, 0, stream>>>(qt, x, Y);              // Y = Q0 x
        gemm_qt<<<256, 256, 0, stream>>>(qt + 262144, Y, out);   // out = Q1 Y
        round_last<<<256, 256, 0, stream>>>(th, out);            // out = G510 out
    } else if (ws_size >= TAB_B) {
        __half2* cs16 = (__half2*)d_ws;
        rotmat_setup<<<511, PAIRS, 0, stream>>>(th, cs16);
        rotmat_main<true><<<N_COLS / 4, 256, 0, stream>>>(x, th, cs16, out);
    } else {
        rotmat_main<false><<<N_COLS / 4, 256, 0, stream>>>(x, th, nullptr, out);
    }
}

// Round 21
// 61.083 us; speedup vs baseline: 1.1352x; 1.1352x over previous
//
#include <hip/hip_runtime.h>
#include <hip/hip_fp16.h>

// RotMat forward: 511 rounds of 256 disjoint Givens rotations on rows of a
// [512, 1024] fp32 matrix (round-robin tournament schedule).
//
// R20: decomposition (R19-proven-correct) with the GEMMs fixed.
// out = (G510*Q1) * (Q0 * x): seg0 = rounds 0..254 (15xCHUNK16 +
// CHUNK15_TAIL, proven), seg1 = rounds 255..510 = 256 rounds via new
// CHUNK16_TAIL (fully drained, no dead reads -- avoids R18's bug structure);
// player_of(511,p) == identity so seg1 writes Q rows directly and the
// round_last launch disappears. GEMMs: R19 indexing (numerically proven) +
// software-pipelined staging (register-prefetch tile kt+1 before computing
// tile kt) + float2 As reads. R19 measured the GEMMs at ~18us each (LDS
// issue-bound + unhidden stage latency); predicted ~6-7 each now.
// ws: [0,512K) f16 table | [512K,1.5M) Q0T | [1.5M,2.5M) Q1T | [2.5M,4.5M) Y.

#define N_COLS   1024
#define PAIRS    256

typedef __attribute__((ext_vector_type(4))) float f32x4;

// ---- setup: f16-packed (c,s) table, round r at byte r*1024, pair k at +k*4.
__global__ __launch_bounds__(256) void rotmat_setup(const float* __restrict__ thetas,
                                                    __half2* __restrict__ cs16) {
    const int r = blockIdx.x;   // 0..510
    const int k = threadIdx.x;  // 0..255
    int pu = (k == 0) ? 0 : ((k - 1 - r + 1022) % 511) + 1;
    int pv = ((510 - k - r + 1022) % 511) + 1;
    int i = min(pu, pv), j = max(pu, pv);
    int t = i * 511 - (i * (i - 1)) / 2 + (j - i - 1);
    float s, c;
    sincosf(thetas[t], &s, &c);
    float sp = (pu < pv) ? s : -s;
    cs16[r * 256 + k] = __floats2half2_rn(c, sp);
}

__device__ __forceinline__ float dpp_shr1(float old, float src) {
    return __int_as_float(__builtin_amdgcn_update_dpp(
        __float_as_int(old), __float_as_int(src), 0x138, 0xF, 0xF, false));
}
__device__ __forceinline__ float dpp_shl1(float old, float src) {
    return __int_as_float(__builtin_amdgcn_update_dpp(
        __float_as_int(old), __float_as_int(src), 0x130, 0xF, 0xF, false));
}
__device__ __forceinline__ void glds16(const void* g, void* l) {
    __builtin_amdgcn_global_load_lds(
        (const __attribute__((address_space(1))) void*)g,
        (__attribute__((address_space(3))) void*)l, 16, 0, 0);
}

// v_fma_mix_f32 coefficient consumption (R16-validated).
#define FMIX_SN(d, P, x)                                                      \
    asm("v_fma_mix_f32 %0, -%1, %2, 0 op_sel:[1,0,0] op_sel_hi:[1,0,0]"       \
        : "=v"(d) : "v"(P), "v"(x));
#define FMIX_SP(d, P, x)                                                      \
    asm("v_fma_mix_f32 %0, %1, %2, 0 op_sel:[1,0,0] op_sel_hi:[1,0,0]"        \
        : "=v"(d) : "v"(P), "v"(x));
#define FMIX_C(d, P, x, a)                                                    \
    asm("v_fma_mix_f32 %0, %1, %2, %3 op_sel:[0,0,0] op_sel_hi:[1,0,0]"       \
        : "=v"(d) : "v"(P), "v"(x), "v"(a));

#define ROUND(AA)                                                  \
    {                                                              \
        float P0 = (AA).x, P1 = (AA).y, P2 = (AA).z, P3 = (AA).w;  \
        float t3, u3, l3, h3, t0, u0, l0, h0;                      \
        FMIX_SN(t3, P3, hi[3])                                     \
        FMIX_C(l3, P3, lo[3], t3)                                  \
        FMIX_SP(u3, P3, lo[3])                                     \
        FMIX_C(h3, P3, hi[3], u3)                                  \
        FMIX_SN(t0, P0, hi[0])                                     \
        FMIX_C(l0, P0, lo[0], t0)                                  \
        FMIX_SP(u0, P0, lo[0])                                     \
        FMIX_C(h0, P0, hi[0], u0)                                  \
        float nlo0 = dpp_shr1(l0, l3);                             \
        float nhi3 = dpp_shl1(l3, h0);                             \
        float t1, u1, l1, h1, t2, u2, l2, h2;                      \
        FMIX_SN(t1, P1, hi[1])                                     \
        FMIX_C(l1, P1, lo[1], t1)                                  \
        FMIX_SP(u1, P1, lo[1])                                     \
        FMIX_C(h1, P1, hi[1], u1)                                  \
        FMIX_SN(t2, P2, hi[2])                                     \
        FMIX_C(l2, P2, lo[2], t2)                                  \
        FMIX_SP(u2, P2, lo[2])                                     \
        FMIX_C(h2, P2, hi[2], u2)                                  \
        float nlo1 = is0 ? h0 : l0;                                \
        lo[0] = nlo0; lo[1] = nlo1; lo[2] = l1; lo[3] = l2;        \
        hi[0] = h1; hi[1] = h2; hi[2] = h3; hi[3] = nhi3;          \
    }

#define DSRD(dst, addr, imm)                                   \
    asm volatile("ds_read_b128 %0, %1 offset:%c2"              \
                 : "=v"(dst) : "v"(addr), "i"(imm))
#define WL3(a) asm volatile("s_waitcnt lgkmcnt(3)" : "+v"(a))
#define WL2(a) asm volatile("s_waitcnt lgkmcnt(2)" : "+v"(a))
#define WL1(a) asm volatile("s_waitcnt lgkmcnt(1)" : "+v"(a))
#define WL0(a) asm volatile("s_waitcnt lgkmcnt(0)" : "+v"(a))
#define WAITV(n) asm volatile("s_waitcnt vmcnt(" #n ")" ::: "memory")
#define BAR()                               \
    __builtin_amdgcn_s_barrier();           \
    __builtin_amdgcn_sched_barrier(0)

#define STAGE(cix, bix)                                              \
    {                                                                \
        const char* g_ = gsrc + (size_t)(cix)*16384;                 \
        char* l_ = lb + (size_t)(bix)*16384;                         \
        _Pragma("unroll")                                            \
        for (int j_ = 0; j_ < 4; ++j_)                               \
            glds16(g_ + j_ * 1024, l_ + j_ * 1024);                  \
    }

#define CHUNK16(ACUR, ANXT)                                    \
    WL3(A0); ROUND(A0) DSRD(A0, ACUR,  4 * 1024);              \
    WL3(A1); ROUND(A1) DSRD(A1, ACUR,  5 * 1024);              \
    WL3(A2); ROUND(A2) DSRD(A2, ACUR,  6 * 1024);              \
    WL3(A3); ROUND(A3) DSRD(A3, ACUR,  7 * 1024);              \
    WL3(A0); ROUND(A0) DSRD(A0, ACUR,  8 * 1024);              \
    WL3(A1); ROUND(A1) DSRD(A1, ACUR,  9 * 1024);              \
    WL3(A2); ROUND(A2) DSRD(A2, ACUR, 10 * 1024);              \
    WL3(A3); ROUND(A3) DSRD(A3, ACUR, 11 * 1024);              \
    WL3(A0); ROUND(A0) DSRD(A0, ACUR, 12 * 1024);              \
    WL3(A1); ROUND(A1) DSRD(A1, ACUR, 13 * 1024);              \
    WL3(A2); ROUND(A2) DSRD(A2, ACUR, 14 * 1024);              \
    WL3(A3); ROUND(A3) DSRD(A3, ACUR, 15 * 1024);              \
    WL3(A0); ROUND(A0) DSRD(A0, ANXT,  0 * 1024);              \
    WL3(A1); ROUND(A1) DSRD(A1, ANXT,  1 * 1024);              \
    WL3(A2); ROUND(A2) DSRD(A2, ANXT,  2 * 1024);              \
    WL3(A3); ROUND(A3) DSRD(A3, ANXT,  3 * 1024);

// 15-round tail (rounds rel 240..254; rel 255 staged, never read). Drained.
#define CHUNK15_TAIL(ACUR)                                     \
    WL3(A0); ROUND(A0) DSRD(A0, ACUR,  4 * 1024);              \
    WL3(A1); ROUND(A1) DSRD(A1, ACUR,  5 * 1024);              \
    WL3(A2); ROUND(A2) DSRD(A2, ACUR,  6 * 1024);              \
    WL3(A3); ROUND(A3) DSRD(A3, ACUR,  7 * 1024);              \
    WL3(A0); ROUND(A0) DSRD(A0, ACUR,  8 * 1024);              \
    WL3(A1); ROUND(A1) DSRD(A1, ACUR,  9 * 1024);              \
    WL3(A2); ROUND(A2) DSRD(A2, ACUR, 10 * 1024);              \
    WL3(A3); ROUND(A3) DSRD(A3, ACUR, 11 * 1024);              \
    WL3(A0); ROUND(A0) DSRD(A0, ACUR, 12 * 1024);              \
    WL3(A1); ROUND(A1) DSRD(A1, ACUR, 13 * 1024);              \
    WL3(A2); ROUND(A2) DSRD(A2, ACUR, 14 * 1024);              \
    WL3(A3); ROUND(A3)                                         \
    WL2(A0); ROUND(A0)                                         \
    WL1(A1); ROUND(A1)                                         \
    WL0(A2); ROUND(A2)

// 16-round tail (rounds rel 240..255, ALL consumed; no dead reads; drained).
// Pending invariant: 4 at entry; reads for rel u+4 issued at u=0..11.
#define CHUNK16_TAIL(ACUR)                                     \
    WL3(A0); ROUND(A0) DSRD(A0, ACUR,  4 * 1024);              \
    WL3(A1); ROUND(A1) DSRD(A1, ACUR,  5 * 1024);              \
    WL3(A2); ROUND(A2) DSRD(A2, ACUR,  6 * 1024);              \
    WL3(A3); ROUND(A3) DSRD(A3, ACUR,  7 * 1024);              \
    WL3(A0); ROUND(A0) DSRD(A0, ACUR,  8 * 1024);              \
    WL3(A1); ROUND(A1) DSRD(A1, ACUR,  9 * 1024);              \
    WL3(A2); ROUND(A2) DSRD(A2, ACUR, 10 * 1024);              \
    WL3(A3); ROUND(A3) DSRD(A3, ACUR, 11 * 1024);              \
    WL3(A0); ROUND(A0) DSRD(A0, ACUR, 12 * 1024);              \
    WL3(A1); ROUND(A1) DSRD(A1, ACUR, 13 * 1024);              \
    WL3(A2); ROUND(A2) DSRD(A2, ACUR, 14 * 1024);              \
    WL3(A3); ROUND(A3) DSRD(A3, ACUR, 15 * 1024);              \
    WL3(A0); ROUND(A0)                                         \
    WL2(A1); ROUND(A1)                                         \
    WL1(A2); ROUND(A2)                                         \
    WL0(A3); ROUND(A3)

// player(r, p): row carried at position p at the start of round r.
// player(511, p) == p (identity).
__device__ __forceinline__ int player_of(int r, int p) {
    return (p == 0) ? 0 : ((p - 1 - r + 1022 * 2) % 511) + 1;
}

// ---- build: seg0 = rounds 0..254 (Q0), seg1 = rounds 255..510 (G510*Q1) --
// 1024 waves; seg = wid>>9 (block-uniform), j = wid&511. QT[seg][j][row].
__global__ __launch_bounds__(256, 1) void rotmat_build(const __half2* __restrict__ cs16,
                                                       float* __restrict__ qt) {
    __shared__ f32x4 tab[3 * 1024];  // 48KB

    const int lane = threadIdx.x & 63;
    const int wave = threadIdx.x >> 6;
    const int wid  = (blockIdx.x << 2) + wave;
    const int seg  = wid >> 9;            // 0 or 1 (uniform per block)
    const int j    = wid & 511;
    const int r0   = seg ? 255 : 0;
    const int k0   = lane << 2;
    const bool is0 = (lane == 0);

    float lo[4], hi[4];
#pragma unroll
    for (int m = 0; m < 4; ++m) {
        int p = k0 + m, pq = 511 - p;
        lo[m] = (player_of(r0, p) == j) ? 1.0f : 0.0f;
        hi[m] = (player_of(r0, pq) == j) ? 1.0f : 0.0f;
    }

    const char* gsrc = (const char*)cs16 + (size_t)r0 * 1024
                     + (size_t)wave * 4096 + (size_t)lane * 16;
    char* lb = (char*)(&tab[0]) + (size_t)wave * 4096;
    unsigned ldsLane;
    {
        auto p3 = (__attribute__((address_space(3))) char*)(&tab[0]);
        ldsLane = (unsigned)(size_t)p3 + (unsigned)(lane * 16);
    }

    f32x4 A0, A1, A2, A3;

    STAGE(0, 0)
    STAGE(1, 1)
    WAITV(0);
    BAR();
    {
        unsigned a0 = ldsLane;
        DSRD(A0, a0, 0 * 1024);
        DSRD(A1, a0, 1 * 1024);
        DSRD(A2, a0, 2 * 1024);
        DSRD(A3, a0, 3 * 1024);
    }

    // 16 chunks. seg0: 15xCHUNK16 + CHUNK15_TAIL (255 rounds; rel 255 = pad,
    // staged unread). seg1: 15xCHUNK16 + CHUNK16_TAIL (256 rounds = abs
    // 255..510, all real table data).
    int bufCur = 0, bufNxt = 1, bufStg = 2;
    for (int c = 0; c < 14; ++c) {
        WAITV(0);
        BAR();
        STAGE(c + 2, bufStg)
        unsigned aCur = ldsLane + (unsigned)bufCur * 16384u;
        unsigned aNxt = ldsLane + (unsigned)bufNxt * 16384u;
        CHUNK16(aCur, aNxt)
        int t_ = bufCur; bufCur = bufNxt; bufNxt = bufStg; bufStg = t_;
    }
    {
        WAITV(0);
        BAR();
        unsigned aCur = ldsLane + (unsigned)bufCur * 16384u;
        unsigned aNxt = ldsLane + (unsigned)bufNxt * 16384u;
        CHUNK16(aCur, aNxt)
        int t_ = bufCur; bufCur = bufNxt; bufNxt = bufStg; bufStg = t_;
    }
    {
        unsigned aCur = ldsLane + (unsigned)bufCur * 16384u;
        if (seg == 0) {
            CHUNK15_TAIL(aCur)
        } else {
            CHUNK16_TAIL(aCur)
        }
    }

    // Write Q_seg^T. seg0: r1=255 map; seg1: r1=511 (identity).
    const int r1 = seg ? 511 : 255;
    float* qv = qt + (size_t)seg * 262144 + (size_t)j * 512;
#pragma unroll
    for (int m = 0; m < 4; ++m) {
        int p = k0 + m, pq = 511 - p;
        qv[player_of(r1, p)]  = lo[m];
        qv[player_of(r1, pq)] = hi[m];
    }
}

// ---- apply: C[512][1024] = sum_j AT[j][row] * B[j][col] -------------------
// AT K-major [512][512]; B row-major [512][1024]. BM=32, BN=64, BK=32.
// R20: software-pipelined staging (register prefetch of tile kt+1 before
// computing tile kt) + float2 As reads. Output indexing identical to R19.
__global__ __launch_bounds__(256) void gemm_qt(const float* __restrict__ AT,
                                               const float* __restrict__ B,
                                               float* __restrict__ C) {
    __shared__ float As[32][32];   // [k][m]
    __shared__ float Bs[32][64];   // [k][n]

    const int t    = threadIdx.x;
    const int bx   = blockIdx.x & 15;   // col tile (64 wide)
    const int by   = blockIdx.x >> 4;   // row tile (32 tall)
    const int row0 = by * 32, col0 = bx * 64;
    const int mr   = (t & 15) * 2;
    const int nc   = (t >> 4) * 4;

    const int kkA = t >> 3, mmA = (t & 7) * 4;   // As stage coords
    const int kkB = t >> 4, ccB = (t & 15) * 4;  // Bs stage coords

    float acc00 = 0, acc01 = 0, acc02 = 0, acc03 = 0;
    float acc10 = 0, acc11 = 0, acc12 = 0, acc13 = 0;

    // Prefetch tile 0.
    float4 pa  = *(const float4*)&AT[(size_t)kkA * 512 + row0 + mmA];
    float4 pb0 = *(const float4*)&B[(size_t)kkB * 1024 + col0 + ccB];
    float4 pb1 = *(const float4*)&B[(size_t)(kkB + 16) * 1024 + col0 + ccB];

    for (int kt = 0; kt < 16; ++kt) {
        __syncthreads();   // previous tile's compute done
        *(float4*)&As[kkA][mmA] = pa;
        *(float4*)&Bs[kkB][ccB] = pb0;
        *(float4*)&Bs[kkB + 16][ccB] = pb1;
        __syncthreads();
        if (kt < 15) {     // prefetch next tile; waits hide under compute
            pa  = *(const float4*)&AT[(size_t)((kt + 1) * 32 + kkA) * 512 + row0 + mmA];
            pb0 = *(const float4*)&B[(size_t)((kt + 1) * 32 + kkB) * 1024 + col0 + ccB];
            pb1 = *(const float4*)&B[(size_t)((kt + 1) * 32 + kkB + 16) * 1024 + col0 + ccB];
        }
#pragma unroll
        for (int kk = 0; kk < 32; ++kk) {
            float2 a = *(float2*)&As[kk][mr];
            float4 b = *(float4*)&Bs[kk][nc];
            acc00 = fmaf(a.x, b.x, acc00); acc01 = fmaf(a.x, b.y, acc01);
            acc02 = fmaf(a.x, b.z, acc02); acc03 = fmaf(a.x, b.w, acc03);
            acc10 = fmaf(a.y, b.x, acc10); acc11 = fmaf(a.y, b.y, acc11);
            acc12 = fmaf(a.y, b.z, acc12); acc13 = fmaf(a.y, b.w, acc13);
        }
    }
    *(float4*)&C[(size_t)(row0 + mr) * 1024 + col0 + nc] =
        make_float4(acc00, acc01, acc02, acc03);
    *(float4*)&C[(size_t)(row0 + mr + 1) * 1024 + col0 + nc] =
        make_float4(acc10, acc11, acc12, acc13);
}

// ---- fallback monolithic kernel (R16-proven, 46.4us) ----------------------
template <bool TAB>
__global__ __launch_bounds__(256, 1) void rotmat_main(const float* __restrict__ x,
                                                      const float* __restrict__ thetas,
                                                      const __half2* __restrict__ cs16,
                                                      float* __restrict__ out) {
    __shared__ f32x4 tab[3 * 1024];

    const int lane = threadIdx.x & 63;
    const int wave = threadIdx.x >> 6;
    const int col  = (blockIdx.x << 2) + wave;
    const int k0   = lane << 2;
    const bool is0 = (lane == 0);

    float lo[4], hi[4];
#pragma unroll
    for (int m = 0; m < 4; ++m) {
        lo[m] = x[(k0 + m) * N_COLS + col];
        hi[m] = x[(511 - k0 - m) * N_COLS + col];
    }

    if constexpr (TAB) {
        const char* gsrc = (const char*)cs16 + (size_t)wave * 4096 + (size_t)lane * 16;
        char* lb = (char*)(&tab[0]) + (size_t)wave * 4096;
        unsigned ldsLane;
        {
            auto p3 = (__attribute__((address_space(3))) char*)(&tab[0]);
            ldsLane = (unsigned)(size_t)p3 + (unsigned)(lane * 16);
        }
        f32x4 A0, A1, A2, A3;
        STAGE(0, 0)
        STAGE(1, 1)
        WAITV(0);
        BAR();
        {
            unsigned a0 = ldsLane;
            DSRD(A0, a0, 0 * 1024);
            DSRD(A1, a0, 1 * 1024);
            DSRD(A2, a0, 2 * 1024);
            DSRD(A3, a0, 3 * 1024);
        }
        int bufCur = 0, bufNxt = 1, bufStg = 2;
        for (int c = 0; c < 30; ++c) {
            WAITV(0);
            BAR();
            STAGE(c + 2, bufStg)
            unsigned aCur = ldsLane + (unsigned)bufCur * 16384u;
            unsigned aNxt = ldsLane + (unsigned)bufNxt * 16384u;
            CHUNK16(aCur, aNxt)
            int t_ = bufCur; bufCur = bufNxt; bufNxt = bufStg; bufStg = t_;
        }
        {
            WAITV(0);
            BAR();
            unsigned aCur = ldsLane + (unsigned)bufCur * 16384u;
            unsigned aNxt = ldsLane + (unsigned)bufNxt * 16384u;
            CHUNK16(aCur, aNxt)
            int t_ = bufCur; bufCur = bufNxt; bufNxt = bufStg; bufStg = t_;
        }
        {
            unsigned aCur = ldsLane + (unsigned)bufCur * 16384u;
            CHUNK15_TAIL(aCur)
        }
    } else {
        int pu[4], pv[4];
#pragma unroll
        for (int m = 0; m < 4; ++m) {
            pu[m] = (k0 + m == 0) ? 0 : (k0 + m);
            pv[m] = 511 - (k0 + m);
        }
        for (int r = 0; r < 511; ++r) {
            float cc[4], ss[4];
#pragma unroll
            for (int m = 0; m < 4; ++m) {
                int i = min(pu[m], pv[m]), jj = max(pu[m], pv[m]);
                int t = i * 511 - (i * (i - 1)) / 2 + (jj - i - 1);
                float s, c;
                sincosf(thetas[t], &s, &c);
                cc[m] = c;
                ss[m] = (pu[m] < pv[m]) ? s : -s;
            }
            {
                float t3 = ss[3] * hi[3], u3 = ss[3] * lo[3];
                float l3 = fmaf(cc[3], lo[3], -t3);
                float h3 = fmaf(cc[3], hi[3], u3);
                float t0 = ss[0] * hi[0], u0 = ss[0] * lo[0];
                float l0 = fmaf(cc[0], lo[0], -t0);
                float h0 = fmaf(cc[0], hi[0], u0);
                float nlo0 = dpp_shr1(l0, l3);
                float nhi3 = dpp_shl1(l3, h0);
                float t1 = ss[1] * hi[1], u1 = ss[1] * lo[1];
                float l1 = fmaf(cc[1], lo[1], -t1);
                float h1 = fmaf(cc[1], hi[1], u1);
                float t2 = ss[2] * hi[2], u2 = ss[2] * lo[2];
                float l2 = fmaf(cc[2], lo[2], -t2);
                float h2 = fmaf(cc[2], hi[2], u2);
                float nlo1 = is0 ? h0 : l0;
                lo[0] = nlo0; lo[1] = nlo1; lo[2] = l1; lo[3] = l2;
                hi[0] = h1; hi[1] = h2; hi[2] = h3; hi[3] = nhi3;
            }
#pragma unroll
            for (int m = 0; m < 4; ++m) {
                pu[m] = (k0 + m == 0) ? 0 : ((pu[m] == 1) ? 511 : pu[m] - 1);
                pv[m] = (pv[m] == 1) ? 511 : pv[m] - 1;
            }
        }
    }

#pragma unroll
    for (int m = 0; m < 4; ++m) {
        out[(k0 + m) * N_COLS + col]       = lo[m];
        out[(511 - k0 - m) * N_COLS + col] = hi[m];
    }
}

extern "C" void kernel_launch(void* const* d_in, const int* in_sizes, int n_in,
                              void* d_out, int out_size, void* d_ws, size_t ws_size,
                              hipStream_t stream) {
    const float* x  = (const float*)d_in[0];
    const float* th = (const float*)d_in[1];
    float* out      = (float*)d_out;

    const size_t TAB_B = (size_t)512 * 1024;          // 512 KiB f16 table
    const size_t Q_B   = (size_t)512 * 512 * 4;       // 1 MiB per segment
    const size_t Y_B   = (size_t)512 * 1024 * 4;      // 2 MiB intermediate
    const size_t need_decomp = TAB_B + 2 * Q_B + Y_B; // 4,718,592

    if (ws_size >= need_decomp) {
        __half2* cs16 = (__half2*)d_ws;
        float* qt = (float*)((char*)d_ws + TAB_B);          // Q0T then (G510*Q1)T
        float* Y  = (float*)((char*)d_ws + TAB_B + 2 * Q_B);
        rotmat_setup<<<511, PAIRS, 0, stream>>>(th, cs16);
        rotmat_build<<<256, 256, 0, stream>>>(cs16, qt);
        gemm_qt<<<256, 256, 0, stream>>>(qt, x, Y);              // Y = Q0 x
        gemm_qt<<<256, 256, 0, stream>>>(qt + 262144, Y, out);   // out = G510 Q1 Y
    } else if (ws_size >= TAB_B) {
        __half2* cs16 = (__half2*)d_ws;
        rotmat_setup<<<511, PAIRS, 0, stream>>>(th, cs16);
        rotmat_main<true><<<N_COLS / 4, 256, 0, stream>>>(x, th, cs16, out);
    } else {
        rotmat_main<false><<<N_COLS / 4, 256, 0, stream>>>(x, th, nullptr, out);
    }
}